// Round 8
// baseline (246.593 us; speedup 1.0000x reference)
//
#include <hip/hip_runtime.h>
#include <math.h>

typedef __attribute__((ext_vector_type(8))) short short8;
typedef __attribute__((ext_vector_type(4))) float floatx4;

__device__ __forceinline__ float bf2f(unsigned short u) {
    union { unsigned int u; float f; } v;
    v.u = ((unsigned int)u) << 16;
    return v.f;
}

__device__ __forceinline__ unsigned short f2bf(float f) {
    union { float f; unsigned int u; } v;
    v.f = f;
    unsigned int r = v.u + 0x7fffu + ((v.u >> 16) & 1u);  // RNE
    return (unsigned short)(r >> 16);
}

// ============================================================================
// Frag-linear (k-major) operand layout: elem (row, k) of an operand with
// RT = rows/16 tiles lives at
//   ((k>>5)*RT + (row>>4))*512 + (row&15)*32 + (k&31)
// A wave's 16x32 MFMA fragment = one contiguous 1KB block; lane l reads 16B
// at (l&15)*64 + (l>>4)*16 bytes -> one fully-coalesced dwordx4 per frag.
// ============================================================================

__device__ __forceinline__ ushort4 cvt4(float4 v, float fa) {
    ushort4 o;
    o.x = f2bf(v.x * fa); o.y = f2bf(v.y * fa);
    o.z = f2bf(v.z * fa); o.w = f2bf(v.w * fa);
    return o;
}

// ---------------- fused prep: rows (wave-per-row) | transpose(value) ----------
// row path: xb[m] (frag-linear, RT=M/16), kf[t] (frag-linear, RT=T/16)
// transpose path: VT (frag-linear over [Dout rows][T k], RT=Dout/16)
__global__ __launch_bounds__(256) void prep_kernel(
    const float* __restrict__ x, const float* __restrict__ key,
    const float* __restrict__ temp, const float* __restrict__ val,
    unsigned short* __restrict__ xb, unsigned short* __restrict__ kf,
    unsigned short* __restrict__ VT, float* __restrict__ rowsq,
    int M, int T, int D, int Dout, int nRowBlocks) {
    const int bid = blockIdx.x;
    if (bid < nRowBlocks) {
        const int lane = threadIdx.x & 63;
        const int nWaves = nRowBlocks << 2;  // 4 waves per block
        const int totRows = M + T;
        for (int row = (bid << 2) | (int)(threadIdx.x >> 6); row < totRows;
             row += nWaves) {
            const bool isx = row < M;
            const int r = isx ? row : row - M;
            const float4* s4 =
                (const float4*)(isx ? (x + (size_t)r * D) : (key + (size_t)r * D));
            float4 v0 = s4[lane];
            float4 v1 = s4[lane + 64];
            float4 v2 = s4[lane + 128];
            float4 v3 = s4[lane + 192];
            float s = v0.x * v0.x + v0.y * v0.y + v0.z * v0.z + v0.w * v0.w;
            s += v1.x * v1.x + v1.y * v1.y + v1.z * v1.z + v1.w * v1.w;
            s += v2.x * v2.x + v2.y * v2.y + v2.z * v2.z + v2.w * v2.w;
            s += v3.x * v3.x + v3.y * v3.y + v3.z * v3.z + v3.w * v3.w;
#pragma unroll
            for (int o = 32; o > 0; o >>= 1) s += __shfl_xor(s, o, 64);
            float fa = 1.0f / fmaxf(sqrtf(s), 1e-12f);
            if (isx) {
                if (lane == 0) rowsq[r] = 0.0f;
            } else {
                fa = fa / (1.0f + expf(-temp[r]));
            }
            unsigned short* dst = isx ? xb : kf;
            const int RT = (isx ? M : T) >> 4;
            const size_t rb = (size_t)(r >> 4) * 512 + (r & 15) * 32;
            // chunk j: k0 = (lane + 64*j)*4; 4 consecutive k in one 32-block
            float4 vv[4] = {v0, v1, v2, v3};
#pragma unroll
            for (int j = 0; j < 4; ++j) {
                const int k0 = (lane + 64 * j) * 4;
                const size_t ad =
                    (size_t)(k0 >> 5) * RT * 512 + rb + (k0 & 31);
                *(ushort4*)(dst + ad) = cvt4(vv[j], fa);
            }
        }
    } else {
        __shared__ unsigned short tile[64][65];
        const int idx = bid - nRowBlocks;
        const int nCt = Dout >> 6;
        const int c0 = (idx % nCt) * 64;
        const int r0 = (idx / nCt) * 64;
        const int t = threadIdx.x;
        const int DT = Dout >> 4;
        for (int i = t; i < 4096; i += 256) {
            int rr = i >> 6, cc = i & 63;
            tile[rr][cc] = f2bf(val[(size_t)(r0 + rr) * Dout + c0 + cc]);
        }
        __syncthreads();
        for (int i = t; i < 4096; i += 256) {
            int rr = i >> 6, cc = i & 63;
            const int o = c0 + rr;   // output-col row of VT
            const int tt = r0 + cc;  // k (= token) index
            const size_t ad = ((size_t)(tt >> 5) * DT + (o >> 4)) * 512 +
                              (o & 15) * 32 + (tt & 31);
            VT[ad] = tile[cc][rr];
        }
    }
}

// ===== 256x256 bf16 MFMA GEMM — LDS-free, direct frag-linear streaming ======
// C[M,N] = A[M,K] * B[N,K]^T; A,B in frag-linear k-major layout.
// 8 waves (2M x 4N), wave = 128x64. Per K-step (32): 8 A-frag + 4 B-frag
// coalesced dwordx4 loads (A shared by 4 waves -> L1; B L2-resident),
// 32 MFMA. 2-deep register pipeline, NO LDS, NO barriers, no inline asm —
// waves run free; compiler schedules loads under MFMAs.
// MODE 0: C = sim (bf16, frag-linear k-major for GEMM2); rowsq[m] += sum^2
// MODE 1: C = out (fp32, row-major [M][N])
template <int MODE>
__global__ __launch_bounds__(512, 2) void gemm_direct(
    const unsigned short* __restrict__ A, const unsigned short* __restrict__ B,
    void* __restrict__ Cv, float* __restrict__ rowsq, int M, int N, int K) {
    const int tid = threadIdx.x;
    const int lane = tid & 63;
    const int w = tid >> 6;   // 0..7
    const int wr = w >> 2;    // 0..1 (M)
    const int wc = w & 3;     // 0..3 (N)
    const int m0 = blockIdx.x * 256;
    const int n0 = blockIdx.y * 256;
    const int q = lane >> 4;
    const int cl = lane & 15;
    const int K32 = K >> 5;
    const int Mt = M >> 4;
    const int Nt = N >> 4;

    const int laneoff = cl * 32 + q * 8;  // elems within a 512-elem block
    // wave bases at kt=0
    const unsigned short* pA =
        A + (size_t)((m0 >> 4) + wr * 8) * 512 + laneoff;
    const unsigned short* pB =
        B + (size_t)((n0 >> 4) + wc * 4) * 512 + laneoff;
    const size_t sA = (size_t)Mt * 512;  // k-step stride (elems)
    const size_t sB = (size_t)Nt * 512;

    floatx4 acc[8][4];
#pragma unroll
    for (int i = 0; i < 8; i++)
#pragma unroll
        for (int j = 0; j < 4; j++) acc[i][j] = (floatx4){0.f, 0.f, 0.f, 0.f};

#define LOADS(AF, BF)                                                        \
    _Pragma("unroll") for (int mt = 0; mt < 8; ++mt)                         \
        AF[mt] = *(const short8*)(pA + mt * 512);                            \
    _Pragma("unroll") for (int nt = 0; nt < 4; ++nt)                         \
        BF[nt] = *(const short8*)(pB + nt * 512);                            \
    pA += sA; pB += sB;

#define STEP(AF, BF)                                                        \
    _Pragma("unroll") for (int mt = 0; mt < 8; ++mt)                        \
        _Pragma("unroll") for (int nt = 0; nt < 4; ++nt)                    \
            acc[mt][nt] = __builtin_amdgcn_mfma_f32_16x16x32_bf16(          \
                AF[mt], BF[nt], acc[mt][nt], 0, 0, 0);

    short8 aA[8], bA[4], aB[8], bB[4];
    LOADS(aA, bA)
    int kt = 0;
    for (; kt + 2 < K32; kt += 2) {
        LOADS(aB, bB)
        STEP(aA, bA)
        LOADS(aA, bA)
        STEP(aB, bB)
    }
    LOADS(aB, bB)
    STEP(aA, bA)
    STEP(aB, bB)
#undef LOADS
#undef STEP

    // epilogue — C/D layout: col = lane&15, row = q*4 + reg
    const int mtb = (m0 >> 4) + wr * 8;
    const int ntb = (n0 >> 5) + wc * 2;
#pragma unroll
    for (int mt = 0; mt < 8; ++mt) {
#pragma unroll
        for (int r = 0; r < 4; ++r) {
            const int m = m0 + wr * 128 + mt * 16 + q * 4 + r;
            if (MODE == 0) {
                unsigned short* C = (unsigned short*)Cv;
                float ssq = 0.f;
#pragma unroll
                for (int nt = 0; nt < 4; ++nt) {
                    float v = acc[mt][nt][r];
                    ssq += v * v;
                    // frag-linear k-major: ((n>>5)*Mt + m-tile)*512 + ...
                    const size_t ad =
                        ((size_t)(ntb + (nt >> 1)) * Mt + (mtb + mt)) * 512 +
                        (q * 4 + r) * 32 + (nt & 1) * 16 + cl;
                    C[ad] = f2bf(v);
                }
#pragma unroll
                for (int o = 1; o < 16; o <<= 1) ssq += __shfl_xor(ssq, o, 64);
                if (cl == 0) atomicAdd(&rowsq[m], ssq);
            } else {
                float* C = (float*)Cv;
#pragma unroll
                for (int nt = 0; nt < 4; ++nt)
                    C[(size_t)m * N + n0 + wc * 64 + nt * 16 + cl] =
                        acc[mt][nt][r];
            }
        }
    }
}

// ---------- in-place: sim = bf16(gelu_exact(sim * sqrt(T)/sqrt(rowsq[row]))) ---
// sim is frag-linear k-major [T/32][M/16][16][32]; a short8 (8 consecutive
// elems) stays within one row of one block. row = mtile*16 + in-block row.
__global__ __launch_bounds__(256) void gelu_kernel(unsigned short* __restrict__ sim,
                                                   const float* __restrict__ rowsq,
                                                   int nVec, int MtMask,
                                                   float sqrtT) {
    const int stride = gridDim.x * blockDim.x;
    const float kk = 0.70710678118654752f;
    for (int i = blockIdx.x * blockDim.x + threadIdx.x; i < nVec; i += stride) {
        short8 v = *(const short8*)(sim + (size_t)i * 8);
        const int row = (((i >> 6) & MtMask) << 4) | ((i >> 2) & 15);
        const float scale = sqrtT / fmaxf(sqrtf(rowsq[row]), 1e-30f);
        short8 o;
#pragma unroll
        for (int j = 0; j < 8; j++) {
            float z = bf2f((unsigned short)v[j]) * scale;
            o[j] = (short)f2bf(0.5f * z * (1.0f + erff(z * kk)));
        }
        *(short8*)(sim + (size_t)i * 8) = o;
    }
}

extern "C" void kernel_launch(void* const* d_in, const int* in_sizes, int n_in,
                              void* d_out, int out_size, void* d_ws, size_t ws_size,
                              hipStream_t stream) {
    const float* x    = (const float*)d_in[0];  // [M, D] fp32
    const float* key  = (const float*)d_in[1];  // [T, D] fp32
    const float* val  = (const float*)d_in[2];  // [T, Dout] fp32
    const float* temp = (const float*)d_in[3];  // [T] fp32
    float* out = (float*)d_out;                 // [M, Dout] fp32

    const int T = in_sizes[3];              // 1024
    const int D = in_sizes[1] / T;          // 1024
    const int Dout = in_sizes[2] / T;       // 1024
    const int M = in_sizes[0] / D;          // 16384

    char* ws = (char*)d_ws;
    size_t off = 0;
    unsigned short* xb  = (unsigned short*)(ws + off); off += (size_t)M * D * 2;
    unsigned short* sim = (unsigned short*)(ws + off); off += (size_t)M * T * 2;
    unsigned short* kf  = (unsigned short*)(ws + off); off += (size_t)T * D * 2;
    unsigned short* VT  = (unsigned short*)(ws + off); off += (size_t)Dout * T * 2;
    float* rowsq = (float*)(ws + off); off += (size_t)M * 4;
    (void)ws_size; (void)n_in; (void)out_size;

    const int nTrTiles = (T >> 6) * (Dout >> 6);
    const int nRowBlocks = 1024;  // 4096 waves grid-striding M+T rows
    prep_kernel<<<nRowBlocks + nTrTiles, 256, 0, stream>>>(
        x, key, temp, val, xb, kf, VT, rowsq, M, T, D, Dout, nRowBlocks);
    gemm_direct<0><<<dim3(M / 256, T / 256), 512, 0, stream>>>(xb, kf, sim,
                                                               rowsq, M, T, D);
    gelu_kernel<<<2048, 256, 0, stream>>>(sim, rowsq, M * (T >> 3), (M >> 4) - 1,
                                          sqrtf((float)T));
    gemm_direct<1><<<dim3(M / 256, Dout / 256), 512, 0, stream>>>(
        sim, VT, out, nullptr, M, Dout, T);
}